// Round 6
// baseline (127.244 us; speedup 1.0000x reference)
//
#include <hip/hip_runtime.h>

// Hapke BRDF — elementwise, N=1M.
// R6 = R5 math + 2 points/thread. Evidence trail: R4 (fewer VALU ops) ~neutral,
// R5 (fewer VMEM ops) ~neutral -> not issue-count-bound. Remaining theory:
// wave-level latency/ILP — one serial dependency chain per wave starves the
// quarter-rate trans pipe. 2 independent chains/wave, VGPR ~64-80 (R3's 4-pt
// version spilled; this is the controlled dose). All loads hoisted ahead.

#define PIF  3.14159265358979323846f
#define EPSF 1e-5f

struct f3 { float x, y, z; };   // 12 B, align 4 -> global_load_dwordx3

__device__ __forceinline__ float rcp(float x)  { return __builtin_amdgcn_rcpf(x); }
__device__ __forceinline__ float rsq(float x)  { return __builtin_amdgcn_rsqf(x); }
__device__ __forceinline__ float sqf(float x)  { return __builtin_amdgcn_sqrtf(x); }
__device__ __forceinline__ float nz(float y, float r) { return (y != y) ? r : y; }
__device__ __forceinline__ float clamp1(float x) { return fminf(fmaxf(x, -1.0f), 1.0f); }
// Abramowitz-Stegun 4.4.45: |err| <= 6.7e-5 rad; phi only feeds phi/PI * E1
// inside a denominator >= ~0.9 — impact ~2e-5 vs 3.18 threshold.
__device__ __forceinline__ float acos_poly(float x) {
    float a = fabsf(x);
    float r = sqf(1.0f - a) *
              (1.5707288f + a * (-0.2121144f + a * (0.0742610f + a * (-0.0187293f))));
    return (x >= 0.0f) ? r : (PIF - r);
}

__global__ __launch_bounds__(256)
void hapke_kernel(const f3* __restrict__ pts2l, const f3* __restrict__ pts2c,
                  const f3* __restrict__ normal, const f3* __restrict__ w,
                  const f3* __restrict__ b, const f3* __restrict__ c,
                  const float2* __restrict__ theta2, const float2* __restrict__ h2,
                  const float2* __restrict__ B02, f3* __restrict__ out, int N2)
{
    int t = blockIdx.x * blockDim.x + threadIdx.x;
    if (t >= N2) return;
    const int i0 = 2 * t;

    // hoist ALL loads — both chains' data in flight before compute starts
    f3 L[2]  = {pts2l[i0],  pts2l[i0+1]};
    f3 V[2]  = {pts2c[i0],  pts2c[i0+1]};
    f3 Nn[2] = {normal[i0], normal[i0+1]};
    f3 wv[2] = {w[i0], w[i0+1]};
    f3 bv[2] = {b[i0], b[i0+1]};
    f3 cc[2] = {c[i0], c[i0+1]};
    float2 thp = theta2[t];
    float2 hp  = h2[t];
    float2 B0p = B02[t];
    const float thA[2] = {thp.x, thp.y};
    const float hA[2]  = {hp.x,  hp.y};
    const float B0A[2] = {B0p.x, B0p.y};

    #pragma unroll
    for (int p = 0; p < 2; ++p) {
        // ci, cv in [0,1] (l,v flipped into normal's hemisphere by setup)
        float ci = clamp1(Nn[p].x*L[p].x + Nn[p].y*L[p].y + Nn[p].z*L[p].z);
        float cv = clamp1(Nn[p].x*V[p].x + Nn[p].y*V[p].y + Nn[p].z*V[p].z);
        float cg = clamp1(L[p].x*V[p].x + L[p].y*V[p].y + L[p].z*V[p].z);
        float si = sqf(1.0f - ci*ci);            // sin(acos x) — exact
        float sv = sqf(1.0f - cv*cv);
        float cphi = clamp1((cg - ci*cv) * rcp(si*sv + 1e-8f));
        float phipi = acos_poly(cphi) * (1.0f / PIF);

        // ff = exp(-2 tan((phi+EPS)/2)) via half-angle; cphi==-1 is the ref's
        // tan overflow -> ff=inf -> NaN -> shad=0 path, preserved explicitly.
        float ffu = (1.0f - cphi) * rcp(1.0f + cphi);
        float ff  = (cphi <= -1.0f) ? __builtin_inff() : __expf(-2.0f * sqf(ffu));

        float s = __sinf(thA[p] + EPSF), cth = __cosf(thA[p] + EPSF);
        float tt     = s * rcp(cth);             // tan(th+EPS); reused for tan(th), diff <= 2e-5
        float cot_th = cth * rcp(s);
        float cot_i  = ci * rcp(si);             // si=0 -> inf -> E*=0 (ref limit)
        float cot_e  = cv * rcp(sv);

        float E1i = nz(__expf(-(2.0f/PIF) * cot_th * cot_i), 0.0f);
        float E1e = nz(__expf(-(2.0f/PIF) * cot_th * cot_e), 0.0f);
        float ct2 = cot_th * cot_th;
        float E2i = nz(__expf(-(1.0f/PIF) * ct2 * cot_i*cot_i), 0.0f);
        float E2e = nz(__expf(-(1.0f/PIF) * ct2 * cot_e*cot_e), 0.0f);

        float chit = rsq(1.0f + PIF * tt * tt);
        float etai = nz(chit * (ci + si * tt * (E2i * rcp(2.0f - E1i))), 0.0f);
        float etae = nz(chit * (cv + sv * tt * (E2e * rcp(2.0f - E1e))), 0.0f);

        float sp2 = 0.5f * (1.0f - cphi);        // sin^2(phi/2) — exact half-angle
        bool  ile = (ci >= cv);                  // sza <= vza (continuous at tie)
        float Ea  = ile ? E1e : E1i;             // shared denominator: select, ONE rcp
        float Eb  = ile ? E1i : E1e;
        float rd  = rcp(2.0f - Ea - phipi * Eb);
        float ymu  = (ile ? (E2e - sp2*E2i)       : (cphi*E2i + sp2*E2e)) * rd;
        float ymu0 = (ile ? (cphi*E2e + sp2*E2i)  : (E2i - sp2*E2e)) * rd;
        float cv_e = nz(chit * (cv + sv * tt * ymu ), cv);    // _mu_eff
        float ci_e = nz(chit * (ci + si * tt * ymu0), ci);    // _mu0_eff

        // _S (shadowing)
        float r_etai = rcp(etai), r_etae = rcp(etae);
        float ci_etai = ci * r_etai, cv_etae = cv * r_etae;
        float temp = cv_e * r_etae * ci_etai * chit;
        float den  = 1.0f - ff + ff * chit * (ile ? ci_etai : cv_etae);
        float shad = nz(temp * rcp(den), 0.0f);  // ff=inf -> den=NaN -> 0 (matches ref)

        // B0/(1 + tan(g/2)/h) + 1 = B0*h/(h+tg2) + 1; tan(g/2)=sqrt((1-cg)/(1+cg))
        float tg2 = sqf((1.0f - cg) * rcp(1.0f + cg));
        float B   = B0A[p] * hA[p] * rcp(hA[p] + tg2) + 1.0f;
        float tmp1 = ci_e * rcp((ci_e + cv_e) * ci);

        float logi = 0.5f * __logf(fabsf((1.0f + ci_e) * rcp(ci_e)));
        float loge = 0.5f * __logf(fabsf((1.0f + cv_e) * rcp(cv_e)));

        float o[3];
        const float W3[3] = {wv[p].x, wv[p].y, wv[p].z};
        const float B3[3] = {bv[p].x, bv[p].y, bv[p].z};
        const float C3[3] = {cc[p].x, cc[p].y, cc[p].z};
        #pragma unroll
        for (int k = 0; k < 3; ++k) {
            float wk = W3[k], bk = B3[k], ck = C3[k];
            float b2 = bk * bk, bx = bk * cg;
            float t1 = 1.0f - 2.0f*bx + b2;      // >= (1-0.8)^2 = 0.04 > 0
            float t2 = 1.0f + 2.0f*bx + b2;
            float q1 = t1 * sqf(t1) + 1e-6f;
            float q2 = t2 * sqf(t2) + 1e-6f;
            float P  = (1.0f - b2) * (ck*q2 + (1.0f - ck)*q1) * rcp(q1*q2);
            float gamma = sqf(1.0f - wk);
            float ro = (1.0f - gamma) * rcp(1.0f + gamma);
            float Hi = nz(rcp(1.0f - wk*ci_e*(ro + (1.0f - 2.0f*ro*ci_e)*logi)), 1.0f);
            float Hv = nz(rcp(1.0f - wk*cv_e*(ro + (1.0f - 2.0f*ro*cv_e)*loge)), 1.0f);
            float tmp2 = P * B + Hi * Hv - 1.0f;
            o[k] = wk * 0.25f * tmp1 * tmp2 * shad;   // w / HPK_SCL
        }
        f3 ov = {o[0], o[1], o[2]};
        out[i0 + p] = ov;                        // one global_store_dwordx3 per point
    }
}

extern "C" void kernel_launch(void* const* d_in, const int* in_sizes, int n_in,
                              void* d_out, int out_size, void* d_ws, size_t ws_size,
                              hipStream_t stream) {
    const f3* pts2l  = (const f3*)d_in[0];
    const f3* pts2c  = (const f3*)d_in[1];
    const f3* normal = (const f3*)d_in[2];
    const f3* w      = (const f3*)d_in[3];
    const f3* b      = (const f3*)d_in[4];
    const f3* c      = (const f3*)d_in[5];
    const float2* theta2 = (const float2*)d_in[6];
    const float2* h2     = (const float2*)d_in[7];
    const float2* B02    = (const float2*)d_in[8];
    f3* out = (f3*)d_out;

    int N  = in_sizes[6];          // N = 1048576, even
    int N2 = N >> 1;               // 2 points per thread
    const int block = 256;
    int grid = (N2 + block - 1) / block;
    hapke_kernel<<<grid, block, 0, stream>>>(pts2l, pts2c, normal, w, b, c,
                                             theta2, h2, B02, out, N2);
}

// Round 7
// 125.357 us; speedup vs baseline: 1.0151x; 1.0151x over previous
//
#include <hip/hip_runtime.h>

// Hapke BRDF — elementwise, N=1M. FINAL (= R4, best measured: 123.9 us total).
// Session evidence: R1 libm-bound 40.6us -> R2 native-intrinsics ~26us (the win).
// Then three orthogonal levers all neutral within noise (~25-28us kernel):
//   R4 -60 VALU ops (25.3), R5 VMEM 24->10 instrs (27), R6 2-pt ILP (28.6).
// Constraint: harness poisons 268MB ws each iter -> L3 evicted -> ~96MB of
// compulsory HBM traffic (~15us floor); measured ~25us = ~3.8TB/s effective
// over 10 load streams + ~900-cycle dependent trans chain. Plateau is
// latency/memory-structural, not issue-count — roofline for this pattern.

#define PIF  3.14159265358979323846f
#define EPSF 1e-5f

__device__ __forceinline__ float rcp(float x)  { return __builtin_amdgcn_rcpf(x); }
__device__ __forceinline__ float rsq(float x)  { return __builtin_amdgcn_rsqf(x); }
__device__ __forceinline__ float sqf(float x)  { return __builtin_amdgcn_sqrtf(x); }
__device__ __forceinline__ float nz(float y, float r) { return (y != y) ? r : y; }
__device__ __forceinline__ float clamp1(float x) { return fminf(fmaxf(x, -1.0f), 1.0f); }
// Abramowitz-Stegun 4.4.45: |err| <= 6.7e-5 rad. phi only feeds phi/PI * E1
// inside a denominator >= ~0.9 — error impact ~2e-5, far under threshold slack.
__device__ __forceinline__ float acos_poly(float x) {
    float a = fabsf(x);
    float r = sqf(1.0f - a) *
              (1.5707288f + a * (-0.2121144f + a * (0.0742610f + a * (-0.0187293f))));
    return (x >= 0.0f) ? r : (PIF - r);
}

__global__ __launch_bounds__(256)
void hapke_kernel(const float* __restrict__ pts2l, const float* __restrict__ pts2c,
                  const float* __restrict__ normal, const float* __restrict__ w,
                  const float* __restrict__ b, const float* __restrict__ c,
                  const float* __restrict__ theta, const float* __restrict__ h,
                  const float* __restrict__ B0, float* __restrict__ out, int N)
{
    int idx = blockIdx.x * blockDim.x + threadIdx.x;
    if (idx >= N) return;
    const int i3 = idx * 3;

    float lx = pts2l[i3], ly = pts2l[i3+1], lz = pts2l[i3+2];
    float vx = pts2c[i3], vy = pts2c[i3+1], vz = pts2c[i3+2];
    float nx = normal[i3], ny = normal[i3+1], nzc = normal[i3+2];

    // ci, cv in [0,1] (l,v flipped into normal's hemisphere by setup)
    float ci = clamp1(nx*lx + ny*ly + nzc*lz);
    float cv = clamp1(nx*vx + ny*vy + nzc*vz);
    float cg = clamp1(lx*vx + ly*vy + lz*vz);
    float si = sqf(1.0f - ci*ci);            // sin(acos x) — exact
    float sv = sqf(1.0f - cv*cv);
    float cphi = clamp1((cg - ci*cv) * rcp(si*sv + 1e-8f));
    float phipi = acos_poly(cphi) * (1.0f / PIF);

    // ff = exp(-2 tan((phi+EPS)/2)) via half-angle; cphi==-1 is the ref's tan
    // overflow -> ff=inf -> NaN -> shad=0 path, preserved explicitly.
    float ffu = (1.0f - cphi) * rcp(1.0f + cphi);
    float ff  = (cphi <= -1.0f) ? __builtin_inff() : __expf(-2.0f * sqf(ffu));

    float th = theta[idx];
    float s = __sinf(th + EPSF), cth = __cosf(th + EPSF);
    float tt     = s * rcp(cth);             // tan(th+EPS); reused for tan(th), diff <= 2e-5
    float cot_th = cth * rcp(s);
    float cot_i  = ci * rcp(si);             // si=0 -> inf -> E*=0 (ref limit)
    float cot_e  = cv * rcp(sv);

    float E1i = nz(__expf(-(2.0f/PIF) * cot_th * cot_i), 0.0f);
    float E1e = nz(__expf(-(2.0f/PIF) * cot_th * cot_e), 0.0f);
    float ct2 = cot_th * cot_th;
    float E2i = nz(__expf(-(1.0f/PIF) * ct2 * cot_i*cot_i), 0.0f);
    float E2e = nz(__expf(-(1.0f/PIF) * ct2 * cot_e*cot_e), 0.0f);

    float chit = rsq(1.0f + PIF * tt * tt);
    float etai = nz(chit * (ci + si * tt * (E2i * rcp(2.0f - E1i))), 0.0f);
    float etae = nz(chit * (cv + sv * tt * (E2e * rcp(2.0f - E1e))), 0.0f);

    float sp2 = 0.5f * (1.0f - cphi);        // sin^2(phi/2) — exact half-angle
    bool  ile = (ci >= cv);                  // sza <= vza (branches continuous at tie)
    float Ea  = ile ? E1e : E1i;             // shared denominator: select, then ONE rcp
    float Eb  = ile ? E1i : E1e;
    float rd  = rcp(2.0f - Ea - phipi * Eb);
    float ymu  = (ile ? (E2e - sp2*E2i)       : (cphi*E2i + sp2*E2e)) * rd;
    float ymu0 = (ile ? (cphi*E2e + sp2*E2i)  : (E2i - sp2*E2e)) * rd;
    float cv_e = nz(chit * (cv + sv * tt * ymu ), cv);    // _mu_eff
    float ci_e = nz(chit * (ci + si * tt * ymu0), ci);    // _mu0_eff

    // _S (shadowing)
    float r_etai = rcp(etai), r_etae = rcp(etae);
    float ci_etai = ci * r_etai, cv_etae = cv * r_etae;
    float temp = cv_e * r_etae * ci_etai * chit;
    float den  = 1.0f - ff + ff * chit * (ile ? ci_etai : cv_etae);
    float shad = nz(temp * rcp(den), 0.0f);  // ff=inf -> den=NaN -> 0 (matches ref)

    // B0/(1 + tan(g/2)/h) + 1 = B0*h/(h + tg2) + 1; tan(g/2)=sqrt((1-cg)/(1+cg))
    float tg2 = sqf((1.0f - cg) * rcp(1.0f + cg));
    float hh  = h[idx];
    float B   = B0[idx] * hh * rcp(hh + tg2) + 1.0f;
    float tmp1 = ci_e * rcp((ci_e + cv_e) * ci);

    float logi = 0.5f * __logf(fabsf((1.0f + ci_e) * rcp(ci_e)));
    float loge = 0.5f * __logf(fabsf((1.0f + cv_e) * rcp(cv_e)));

    #pragma unroll
    for (int k = 0; k < 3; ++k) {
        float wk = w[i3+k], bk = b[i3+k], ck = c[i3+k];
        float b2 = bk * bk, bx = bk * cg;
        float t1 = 1.0f - 2.0f*bx + b2;      // >= (1-0.8)^2 = 0.04 > 0
        float t2 = 1.0f + 2.0f*bx + b2;
        float q1 = t1 * sqf(t1) + 1e-6f;
        float q2 = t2 * sqf(t2) + 1e-6f;
        float P  = (1.0f - b2) * (ck*q2 + (1.0f - ck)*q1) * rcp(q1*q2);
        float gamma = sqf(1.0f - wk);
        float ro = (1.0f - gamma) * rcp(1.0f + gamma);
        float Hi = nz(rcp(1.0f - wk*ci_e*(ro + (1.0f - 2.0f*ro*ci_e)*logi)), 1.0f);
        float Hv = nz(rcp(1.0f - wk*cv_e*(ro + (1.0f - 2.0f*ro*cv_e)*loge)), 1.0f);
        float tmp2 = P * B + Hi * Hv - 1.0f;
        out[i3+k] = wk * 0.25f * tmp1 * tmp2 * shad;   // w / HPK_SCL
    }
}

extern "C" void kernel_launch(void* const* d_in, const int* in_sizes, int n_in,
                              void* d_out, int out_size, void* d_ws, size_t ws_size,
                              hipStream_t stream) {
    const float* pts2l  = (const float*)d_in[0];
    const float* pts2c  = (const float*)d_in[1];
    const float* normal = (const float*)d_in[2];
    const float* w      = (const float*)d_in[3];
    const float* b      = (const float*)d_in[4];
    const float* c      = (const float*)d_in[5];
    const float* theta  = (const float*)d_in[6];
    const float* h      = (const float*)d_in[7];
    const float* B0     = (const float*)d_in[8];
    float* out = (float*)d_out;

    int N = in_sizes[6];
    const int block = 256;
    int grid = (N + block - 1) / block;
    hapke_kernel<<<grid, block, 0, stream>>>(pts2l, pts2c, normal, w, b, c,
                                             theta, h, B0, out, N);
}